// Round 3
// baseline (262.078 us; speedup 1.0000x reference)
//
#include <hip/hip_runtime.h>

#define N_NODES 50000
#define N_EDGES 800000
#define IN_DIM 256
#define HID_DIM 128
#define OUT_DIM 64
#define CAP 64      // per-node bucket capacity; deg ~Poisson(16), max over 50k ~40
#define NPAD 50176  // node-padded plane stride (256*196)

// two-phase binning
#define K_BINS 256
#define NPB 196     // nodes per bin: 256*196 = 50176 >= 50000
#define BINCAP 4096 // expected 3125/bin, sigma ~56 -> 17-sigma headroom
#define CHUNK 4096  // edges per k_bin workgroup
#define N_BINWG 196 // ceil(800000/4096)

// agg node-blocks (4 nodes per 256-thr wg)
#define N_NB 12500

typedef __bf16 bf16x8 __attribute__((ext_vector_type(8)));
typedef float f32x4 __attribute__((ext_vector_type(4)));
typedef unsigned short u16x8 __attribute__((ext_vector_type(8)));
typedef unsigned short ushort_t;
typedef unsigned int uint_t;

// float -> bf16 bits, round-to-nearest-even (finite values)
__device__ __forceinline__ ushort_t f2bf(float f) {
    uint_t u = __float_as_uint(f);
    return (ushort_t)((u + 0x7fffu + ((u >> 16) & 1u)) >> 16);
}
__device__ __forceinline__ float bf_lo(uint_t u) { return __uint_as_float(u << 16); }
__device__ __forceinline__ float bf_hi(uint_t u) { return __uint_as_float(u & 0xffff0000u); }

// ---------------- launch 2: cast/transpose weights ----------------
__global__ __launch_bounds__(256) void k_init(const float* __restrict__ W1,
                                              ushort_t* __restrict__ w1t,
                                              const float* __restrict__ W2,
                                              ushort_t* __restrict__ w2t) {
    const int bid = blockIdx.x;
    const int t = threadIdx.x;
    if (bid < 128) {                       // W1 [256x128] -> w1t [128x256] bf16
        int id = bid * 256 + t;
        int k = id >> 7, c = id & 127;
        w1t[c * IN_DIM + k] = f2bf(W1[id]);
    } else {                               // W2 [128x64] -> w2t [64x128] bf16
        int id = (bid - 128) * 256 + t;
        int k = id >> 6, c = id & 63;
        w2t[c * HID_DIM + k] = f2bf(W2[id]);
    }
}

// ---------------- launch 3a: bin edges by dst range ----------------
__global__ __launch_bounds__(256) void k_bin(const int* __restrict__ srcs,
                                             const int* __restrict__ dsts,
                                             int* __restrict__ bin_cur,
                                             uint_t* __restrict__ binbuf) {
    __shared__ int lcnt[K_BINS];
    __shared__ int lbase[K_BINS];
    const int t = threadIdx.x;
    lcnt[t] = 0;
    __syncthreads();
    const int start = blockIdx.x * CHUNK;
    int b_[16]; int p_[16]; uint_t rec_[16];
#pragma unroll
    for (int k = 0; k < 16; ++k) {
        int e = start + t + k * 256;
        bool ok = (e < N_EDGES);
        int d = ok ? dsts[e] : 0;
        int s = ok ? srcs[e] : 0;
        int b = d / NPB;                       // magic-mul, NPB is compile-time
        b_[k] = ok ? b : -1;
        p_[k] = ok ? atomicAdd(&lcnt[b], 1) : 0;
        rec_[k] = (uint_t)s | ((uint_t)(d - b * NPB) << 16);  // src < 65536, dl < 196
    }
    __syncthreads();
    lbase[t] = atomicAdd(&bin_cur[t], lcnt[t]);   // 256 atomics/wg
    __syncthreads();
#pragma unroll
    for (int k = 0; k < 16; ++k) {
        if (b_[k] >= 0) {
            int pos = lbase[b_[k]] + p_[k];
            if (pos < BINCAP) binbuf[(size_t)b_[k] * BINCAP + pos] = rec_[k];
        }
    }
}

// ---------------- launch 3b: fill es buckets, one wg per bin ----------------
__global__ __launch_bounds__(256) void k_fill(const int* __restrict__ bin_cur,
                                              const uint_t* __restrict__ binbuf,
                                              ushort_t* __restrict__ es,
                                              float* __restrict__ dinv,
                                              int* __restrict__ ndeg) {
    __shared__ int cnt[NPB];
    __shared__ __align__(16) ushort_t pay[NPB][CAP];   // 25088 B
    const int b = blockIdx.x, t = threadIdx.x;
    if (t < NPB) cnt[t] = 0;
    __syncthreads();
    const int n = min(bin_cur[b], BINCAP);
    const uint_t* rec = binbuf + (size_t)b * BINCAP;
    for (int e = t; e < n; e += 256) {
        uint_t r = rec[e];
        int dl = r >> 16;
        int p = atomicAdd(&cnt[dl], 1);
        if (p < CAP) pay[dl][p] = (ushort_t)(r & 0xffffu);
    }
    __syncthreads();
    uint4* gdst = (uint4*)(es + (size_t)b * NPB * CAP);
    const uint4* lsrc = (const uint4*)&pay[0][0];
    for (int i = t; i < NPB * CAP / 8; i += 256) gdst[i] = lsrc[i];
    if (t < NPB) {
        int node = b * NPB + t;
        if (node < N_NODES) {
            int deg = cnt[t];
            dinv[node] = rsqrtf((float)(deg + 1));
            ndeg[node] = min(deg, CAP);
        }
    }
}

// ---------------- launch 4: gemm1 (MFMA): hb planes = x @ W1 ----------------
// hb stored as 4 channel planes [4][NPAD][32] bf16 (3.2 MB each, fits XCD L2)
__global__ __launch_bounds__(64) void k_gemm1(const float* __restrict__ x,
                                              const ushort_t* __restrict__ w1t,
                                              ushort_t* __restrict__ hbp) {
    const int lane = threadIdx.x;
    const int l15 = lane & 15, quad = lane >> 4;
    const int row = blockIdx.x * 16 + l15;
    f32x4 acc[8];
#pragma unroll
    for (int n = 0; n < 8; ++n) acc[n] = (f32x4){0.f, 0.f, 0.f, 0.f};
    const float* xrow = x + (size_t)row * IN_DIM + quad * 8;
    const ushort_t* wbase = w1t + quad * 8;
#pragma unroll
    for (int t = 0; t < 8; ++t) {
        const float4* xp = (const float4*)(xrow + t * 32);
        float4 f0 = xp[0], f1 = xp[1];
        u16x8 au;
        au[0] = f2bf(f0.x); au[1] = f2bf(f0.y); au[2] = f2bf(f0.z); au[3] = f2bf(f0.w);
        au[4] = f2bf(f1.x); au[5] = f2bf(f1.y); au[6] = f2bf(f1.z); au[7] = f2bf(f1.w);
        bf16x8 a = __builtin_bit_cast(bf16x8, au);
#pragma unroll
        for (int n = 0; n < 8; ++n) {
            bf16x8 b = *(const bf16x8*)(wbase + (n * 16 + l15) * IN_DIM + t * 32);
            acc[n] = __builtin_amdgcn_mfma_f32_16x16x32_bf16(a, b, acc[n], 0, 0, 0);
        }
    }
    // C/D layout: col = lane&15, row = quad*4 + r; channel c=n*16+l15 -> plane c>>5
    const int orow0 = blockIdx.x * 16 + quad * 4;
#pragma unroll
    for (int n = 0; n < 8; ++n) {
        ushort_t* pl = hbp + ((size_t)(n >> 1) * NPAD + orow0) * 32 + (n & 1) * 16 + l15;
#pragma unroll
        for (int r = 0; r < 4; ++r)
            pl[(size_t)r * 32] = f2bf(acc[n][r]);
    }
}

// ---------------- launch 5: agg1 (quarter-phased planes + 8-deep MLP) ----------------
// R2 post-mortem: dynamic-bound loop gave only 2 gathers in flight -> latency-bound
// at 1.1 TB/s. Fix: 32 edges/iter (8 rounds x 4 lane-groups), 8 independent loads
// per lane in flight. Slots past n have nmj=0 and sj=0 (all junk gathers alias one
// L1-resident line). es staging loads are nontemporal to spare L2 plane residency.
__global__ __launch_bounds__(256) void k_agg1(const ushort_t* __restrict__ hbp,
                                              const int* __restrict__ ndeg,
                                              const float* __restrict__ dinv,
                                              const ushort_t* __restrict__ es,
                                              const float* __restrict__ b,
                                              ushort_t* __restrict__ hrelup) {
    const int q = blockIdx.x / N_NB;
    const int i = (blockIdx.x - q * N_NB) * 4 + (threadIdx.x >> 6);
    const int lane = threadIdx.x & 63;
    const int g = lane >> 4;           // edge subgroup 0..3
    const int ch = lane & 15;          // channel-pair within plane (2 ch)
    const float dv = dinv[i];
    const int n = ndeg[i];
    int   sj = 0;
    float nmj = 0.f;
    if (lane < n) {
        sj = (int)__builtin_nontemporal_load(&es[i * CAP + lane]);
        nmj = dinv[sj] * dv;
    }
    const ushort_t* hq = hbp + (size_t)q * NPAD * 32;
    float accA = 0.f, accB = 0.f;
    for (int j = 0; j < n; j += 32) {  // 32 edges per iter: 8 rounds of 4 groups
        int   s0 = __shfl(sj, j + g),      s1 = __shfl(sj, j + 4 + g);
        int   s2 = __shfl(sj, j + 8 + g),  s3 = __shfl(sj, j + 12 + g);
        int   s4 = __shfl(sj, j + 16 + g), s5 = __shfl(sj, j + 20 + g);
        int   s6 = __shfl(sj, j + 24 + g), s7 = __shfl(sj, j + 28 + g);
        float m0 = __shfl(nmj, j + g),      m1 = __shfl(nmj, j + 4 + g);
        float m2 = __shfl(nmj, j + 8 + g),  m3 = __shfl(nmj, j + 12 + g);
        float m4 = __shfl(nmj, j + 16 + g), m5 = __shfl(nmj, j + 20 + g);
        float m6 = __shfl(nmj, j + 24 + g), m7 = __shfl(nmj, j + 28 + g);
        uint_t v0 = *(const uint_t*)(hq + (size_t)s0 * 32 + 2 * ch);
        uint_t v1 = *(const uint_t*)(hq + (size_t)s1 * 32 + 2 * ch);
        uint_t v2 = *(const uint_t*)(hq + (size_t)s2 * 32 + 2 * ch);
        uint_t v3 = *(const uint_t*)(hq + (size_t)s3 * 32 + 2 * ch);
        uint_t v4 = *(const uint_t*)(hq + (size_t)s4 * 32 + 2 * ch);
        uint_t v5 = *(const uint_t*)(hq + (size_t)s5 * 32 + 2 * ch);
        uint_t v6 = *(const uint_t*)(hq + (size_t)s6 * 32 + 2 * ch);
        uint_t v7 = *(const uint_t*)(hq + (size_t)s7 * 32 + 2 * ch);
        accA += bf_lo(v0) * m0 + bf_lo(v1) * m1 + bf_lo(v2) * m2 + bf_lo(v3) * m3
              + bf_lo(v4) * m4 + bf_lo(v5) * m5 + bf_lo(v6) * m6 + bf_lo(v7) * m7;
        accB += bf_hi(v0) * m0 + bf_hi(v1) * m1 + bf_hi(v2) * m2 + bf_hi(v3) * m3
              + bf_hi(v4) * m4 + bf_hi(v5) * m5 + bf_hi(v6) * m6 + bf_hi(v7) * m7;
    }
    // reduce the 4 groups (lane bits 4,5)
    accA += __shfl_xor(accA, 16); accA += __shfl_xor(accA, 32);
    accB += __shfl_xor(accB, 16); accB += __shfl_xor(accB, 32);
    if (lane < 16) {
        uint_t u = *(const uint_t*)(hq + (size_t)i * 32 + 2 * ch);   // self loop
        float v0 = accA + bf_lo(u) * dv * dv + b[q * 32 + 2 * ch];
        float v1 = accB + bf_hi(u) * dv * dv + b[q * 32 + 2 * ch + 1];
        v0 = v0 > 0.f ? v0 : 0.f;
        v1 = v1 > 0.f ? v1 : 0.f;
        *(uint_t*)(hrelup + ((size_t)q * NPAD + i) * 32 + 2 * ch) =
            ((uint_t)f2bf(v1) << 16) | f2bf(v0);
    }
}

// ---------------- launch 6: gemm2 (MFMA): h2 planes = hrelu @ W2 ----------------
__global__ __launch_bounds__(64) void k_gemm2(const ushort_t* __restrict__ hrelup,
                                              const ushort_t* __restrict__ w2t,
                                              ushort_t* __restrict__ h2p) {
    const int lane = threadIdx.x;
    const int l15 = lane & 15, quad = lane >> 4;
    const int row = blockIdx.x * 16 + l15;
    f32x4 acc[4];
#pragma unroll
    for (int n = 0; n < 4; ++n) acc[n] = (f32x4){0.f, 0.f, 0.f, 0.f};
    const ushort_t* wbase = w2t + quad * 8;
#pragma unroll
    for (int t = 0; t < 4; ++t) {
        bf16x8 a = *(const bf16x8*)(hrelup + ((size_t)t * NPAD + row) * 32 + quad * 8);
#pragma unroll
        for (int n = 0; n < 4; ++n) {
            bf16x8 b = *(const bf16x8*)(wbase + (n * 16 + l15) * HID_DIM + t * 32);
            acc[n] = __builtin_amdgcn_mfma_f32_16x16x32_bf16(a, b, acc[n], 0, 0, 0);
        }
    }
    const int orow0 = blockIdx.x * 16 + quad * 4;
#pragma unroll
    for (int n = 0; n < 4; ++n) {
        ushort_t* pl = h2p + ((size_t)(n >> 1) * NPAD + orow0) * 32 + (n & 1) * 16 + l15;
#pragma unroll
        for (int r = 0; r < 4; ++r)
            pl[(size_t)r * 32] = f2bf(acc[n][r]);
    }
}

// ---------------- launch 7: agg2 (half-phased planes + 8-deep MLP) ----------------
__global__ __launch_bounds__(256) void k_agg2(const ushort_t* __restrict__ h2p,
                                              const int* __restrict__ ndeg,
                                              const float* __restrict__ dinv,
                                              const ushort_t* __restrict__ es,
                                              const float* __restrict__ b,
                                              float* __restrict__ out) {
    const int h = blockIdx.x / N_NB;
    const int i = (blockIdx.x - h * N_NB) * 4 + (threadIdx.x >> 6);
    const int lane = threadIdx.x & 63;
    const int g = lane >> 4;
    const int ch = lane & 15;
    const float dv = dinv[i];
    const int n = ndeg[i];
    int   sj = 0;
    float nmj = 0.f;
    if (lane < n) {
        sj = (int)__builtin_nontemporal_load(&es[i * CAP + lane]);
        nmj = dinv[sj] * dv;
    }
    const ushort_t* hq = h2p + (size_t)h * NPAD * 32;
    float accA = 0.f, accB = 0.f;
    for (int j = 0; j < n; j += 32) {
        int   s0 = __shfl(sj, j + g),      s1 = __shfl(sj, j + 4 + g);
        int   s2 = __shfl(sj, j + 8 + g),  s3 = __shfl(sj, j + 12 + g);
        int   s4 = __shfl(sj, j + 16 + g), s5 = __shfl(sj, j + 20 + g);
        int   s6 = __shfl(sj, j + 24 + g), s7 = __shfl(sj, j + 28 + g);
        float m0 = __shfl(nmj, j + g),      m1 = __shfl(nmj, j + 4 + g);
        float m2 = __shfl(nmj, j + 8 + g),  m3 = __shfl(nmj, j + 12 + g);
        float m4 = __shfl(nmj, j + 16 + g), m5 = __shfl(nmj, j + 20 + g);
        float m6 = __shfl(nmj, j + 24 + g), m7 = __shfl(nmj, j + 28 + g);
        uint_t v0 = *(const uint_t*)(hq + (size_t)s0 * 32 + 2 * ch);
        uint_t v1 = *(const uint_t*)(hq + (size_t)s1 * 32 + 2 * ch);
        uint_t v2 = *(const uint_t*)(hq + (size_t)s2 * 32 + 2 * ch);
        uint_t v3 = *(const uint_t*)(hq + (size_t)s3 * 32 + 2 * ch);
        uint_t v4 = *(const uint_t*)(hq + (size_t)s4 * 32 + 2 * ch);
        uint_t v5 = *(const uint_t*)(hq + (size_t)s5 * 32 + 2 * ch);
        uint_t v6 = *(const uint_t*)(hq + (size_t)s6 * 32 + 2 * ch);
        uint_t v7 = *(const uint_t*)(hq + (size_t)s7 * 32 + 2 * ch);
        accA += bf_lo(v0) * m0 + bf_lo(v1) * m1 + bf_lo(v2) * m2 + bf_lo(v3) * m3
              + bf_lo(v4) * m4 + bf_lo(v5) * m5 + bf_lo(v6) * m6 + bf_lo(v7) * m7;
        accB += bf_hi(v0) * m0 + bf_hi(v1) * m1 + bf_hi(v2) * m2 + bf_hi(v3) * m3
              + bf_hi(v4) * m4 + bf_hi(v5) * m5 + bf_hi(v6) * m6 + bf_hi(v7) * m7;
    }
    accA += __shfl_xor(accA, 16); accA += __shfl_xor(accA, 32);
    accB += __shfl_xor(accB, 16); accB += __shfl_xor(accB, 32);
    if (lane < 16) {
        uint_t u = *(const uint_t*)(hq + (size_t)i * 32 + 2 * ch);   // self loop
        float2 r;
        r.x = accA + bf_lo(u) * dv * dv + b[h * 32 + 2 * ch];
        r.y = accB + bf_hi(u) * dv * dv + b[h * 32 + 2 * ch + 1];
        *(float2*)(out + (size_t)i * OUT_DIM + h * 32 + 2 * ch) = r;
    }
}

extern "C" void kernel_launch(void* const* d_in, const int* in_sizes, int n_in,
                              void* d_out, int out_size, void* d_ws, size_t ws_size,
                              hipStream_t stream) {
    const float* x   = (const float*)d_in[0];
    const int*   ei  = (const int*)d_in[1];    // [2, E] int32
    const float* W1  = (const float*)d_in[2];
    const float* b1  = (const float*)d_in[3];
    const float* W2  = (const float*)d_in[4];
    const float* b2  = (const float*)d_in[5];
    float* out = (float*)d_out;

    const int* srcs = ei;             // edge_index[0]
    const int* dsts = ei + N_EDGES;   // edge_index[1]

    // workspace (~50 MB)
    char* ws = (char*)d_ws;
    size_t o = 0;
    auto alloc = [&](size_t bytes) { void* p = ws + o; o = (o + bytes + 511) & ~size_t(511); return p; };
    int*      bin_cur = (int*)   alloc(K_BINS * 4);
    float*    dinv  = (float*)   alloc(N_NODES * 4);
    int*      ndeg  = (int*)     alloc(N_NODES * 4);
    ushort_t* es    = (ushort_t*)alloc((size_t)K_BINS * NPB * CAP * 2);  // padded to 50176 nodes
    uint_t*   binbuf= (uint_t*)  alloc((size_t)K_BINS * BINCAP * 4);     // 4 MB
    ushort_t* w1t   = (ushort_t*)alloc((size_t)IN_DIM * HID_DIM * 2);
    ushort_t* w2t   = (ushort_t*)alloc((size_t)HID_DIM * OUT_DIM * 2);
    ushort_t* hbp   = (ushort_t*)alloc((size_t)4 * NPAD * 32 * 2);       // 4 planes x 3.2 MB
    ushort_t* hrelup= (ushort_t*)alloc((size_t)4 * NPAD * 32 * 2);
    ushort_t* h2p   = (ushort_t*)alloc((size_t)2 * NPAD * 32 * 2);       // 2 planes

    hipMemsetAsync(bin_cur, 0, K_BINS * 4, stream);
    k_init  <<<160, 256, 0, stream>>>(W1, w1t, W2, w2t);
    k_bin   <<<N_BINWG, 256, 0, stream>>>(srcs, dsts, bin_cur, binbuf);
    k_fill  <<<K_BINS, 256, 0, stream>>>(bin_cur, binbuf, es, dinv, ndeg);
    k_gemm1 <<<N_NODES / 16, 64, 0, stream>>>(x, w1t, hbp);
    k_agg1  <<<4 * N_NB, 256, 0, stream>>>(hbp, ndeg, dinv, es, b1, hrelup);
    k_gemm2 <<<N_NODES / 16, 64, 0, stream>>>(hrelup, w2t, h2p);
    k_agg2  <<<2 * N_NB, 256, 0, stream>>>(h2p, ndeg, dinv, es, b2, out);
}

// Round 4
// 220.893 us; speedup vs baseline: 1.1864x; 1.1864x over previous
//
#include <hip/hip_runtime.h>

#define N_NODES 50000
#define N_EDGES 800000
#define IN_DIM 256
#define HID_DIM 128
#define OUT_DIM 64
#define CAP 64      // per-node bucket capacity; deg ~Poisson(16), max over 50k ~40

// two-phase binning
#define K_BINS 256
#define NPB 196     // nodes per bin: 256*196 = 50176 >= 50000
#define BINCAP 4096 // expected 3125/bin, sigma ~56 -> 17-sigma headroom
#define CHUNK 4096  // edges per k_bin workgroup
#define N_BINWG 196 // ceil(800000/4096)

typedef __bf16 bf16x8 __attribute__((ext_vector_type(8)));
typedef float f32x4 __attribute__((ext_vector_type(4)));
typedef unsigned short u16x8 __attribute__((ext_vector_type(8)));
typedef unsigned short ushort_t;
typedef unsigned int uint_t;

// float -> bf16 bits, round-to-nearest-even (finite values)
__device__ __forceinline__ ushort_t f2bf(float f) {
    uint_t u = __float_as_uint(f);
    return (ushort_t)((u + 0x7fffu + ((u >> 16) & 1u)) >> 16);
}
__device__ __forceinline__ float bf_lo(uint_t u) { return __uint_as_float(u << 16); }
__device__ __forceinline__ float bf_hi(uint_t u) { return __uint_as_float(u & 0xffff0000u); }

// ---------------- launch 2: cast/transpose weights ----------------
__global__ __launch_bounds__(256) void k_init(const float* __restrict__ W1,
                                              ushort_t* __restrict__ w1t,
                                              const float* __restrict__ W2,
                                              ushort_t* __restrict__ w2t) {
    const int bid = blockIdx.x;
    const int t = threadIdx.x;
    if (bid < 128) {                       // W1 [256x128] -> w1t [128x256] bf16
        int id = bid * 256 + t;
        int k = id >> 7, c = id & 127;
        w1t[c * IN_DIM + k] = f2bf(W1[id]);
    } else {                               // W2 [128x64] -> w2t [64x128] bf16
        int id = (bid - 128) * 256 + t;
        int k = id >> 6, c = id & 63;
        w2t[c * HID_DIM + k] = f2bf(W2[id]);
    }
}

// ---------------- launch 3a: bin edges by dst range ----------------
__global__ __launch_bounds__(256) void k_bin(const int* __restrict__ srcs,
                                             const int* __restrict__ dsts,
                                             int* __restrict__ bin_cur,
                                             uint_t* __restrict__ binbuf) {
    __shared__ int lcnt[K_BINS];
    __shared__ int lbase[K_BINS];
    const int t = threadIdx.x;
    lcnt[t] = 0;
    __syncthreads();
    const int start = blockIdx.x * CHUNK;
    int b_[16]; int p_[16]; uint_t rec_[16];
#pragma unroll
    for (int k = 0; k < 16; ++k) {
        int e = start + t + k * 256;
        bool ok = (e < N_EDGES);
        int d = ok ? dsts[e] : 0;
        int s = ok ? srcs[e] : 0;
        int b = d / NPB;                       // magic-mul, NPB is compile-time
        b_[k] = ok ? b : -1;
        p_[k] = ok ? atomicAdd(&lcnt[b], 1) : 0;
        rec_[k] = (uint_t)s | ((uint_t)(d - b * NPB) << 16);  // src < 65536, dl < 196
    }
    __syncthreads();
    lbase[t] = atomicAdd(&bin_cur[t], lcnt[t]);   // 256 atomics/wg
    __syncthreads();
#pragma unroll
    for (int k = 0; k < 16; ++k) {
        if (b_[k] >= 0) {
            int pos = lbase[b_[k]] + p_[k];
            if (pos < BINCAP) binbuf[(size_t)b_[k] * BINCAP + pos] = rec_[k];
        }
    }
}

// ---------------- launch 3b: fill es buckets, one wg per bin ----------------
__global__ __launch_bounds__(256) void k_fill(const int* __restrict__ bin_cur,
                                              const uint_t* __restrict__ binbuf,
                                              ushort_t* __restrict__ es,
                                              float* __restrict__ dinv,
                                              int* __restrict__ ndeg) {
    __shared__ int cnt[NPB];
    __shared__ __align__(16) ushort_t pay[NPB][CAP];   // 25088 B
    const int b = blockIdx.x, t = threadIdx.x;
    if (t < NPB) cnt[t] = 0;
    __syncthreads();
    const int n = min(bin_cur[b], BINCAP);
    const uint_t* rec = binbuf + (size_t)b * BINCAP;
    for (int e = t; e < n; e += 256) {
        uint_t r = rec[e];
        int dl = r >> 16;
        int p = atomicAdd(&cnt[dl], 1);
        if (p < CAP) pay[dl][p] = (ushort_t)(r & 0xffffu);
    }
    __syncthreads();
    uint4* gdst = (uint4*)(es + (size_t)b * NPB * CAP);
    const uint4* lsrc = (const uint4*)&pay[0][0];
    for (int i = t; i < NPB * CAP / 8; i += 256) gdst[i] = lsrc[i];
    if (t < NPB) {
        int node = b * NPB + t;
        if (node < N_NODES) {
            int deg = cnt[t];
            dinv[node] = rsqrtf((float)(deg + 1));
            ndeg[node] = min(deg, CAP);
        }
    }
}

// ---------------- launch 4: gemm1 (MFMA): hb(bf16, [N][128]) = x @ W1 ----------------
__global__ __launch_bounds__(64) void k_gemm1(const float* __restrict__ x,
                                              const ushort_t* __restrict__ w1t,
                                              ushort_t* __restrict__ hb) {
    const int lane = threadIdx.x;
    const int l15 = lane & 15, quad = lane >> 4;
    const int row = blockIdx.x * 16 + l15;
    f32x4 acc[8];
#pragma unroll
    for (int n = 0; n < 8; ++n) acc[n] = (f32x4){0.f, 0.f, 0.f, 0.f};
    const float* xrow = x + (size_t)row * IN_DIM + quad * 8;
    const ushort_t* wbase = w1t + quad * 8;
#pragma unroll
    for (int t = 0; t < 8; ++t) {
        const float4* xp = (const float4*)(xrow + t * 32);
        float4 f0 = xp[0], f1 = xp[1];
        u16x8 au;
        au[0] = f2bf(f0.x); au[1] = f2bf(f0.y); au[2] = f2bf(f0.z); au[3] = f2bf(f0.w);
        au[4] = f2bf(f1.x); au[5] = f2bf(f1.y); au[6] = f2bf(f1.z); au[7] = f2bf(f1.w);
        bf16x8 a = __builtin_bit_cast(bf16x8, au);
#pragma unroll
        for (int n = 0; n < 8; ++n) {
            bf16x8 b = *(const bf16x8*)(wbase + (n * 16 + l15) * IN_DIM + t * 32);
            acc[n] = __builtin_amdgcn_mfma_f32_16x16x32_bf16(a, b, acc[n], 0, 0, 0);
        }
    }
    // C/D layout: col = lane&15, row = quad*4 + r  [measured m89/m91]
    ushort_t* hrow = hb + ((size_t)blockIdx.x * 16 + quad * 4) * HID_DIM + l15;
#pragma unroll
    for (int n = 0; n < 8; ++n)
#pragma unroll
        for (int r = 0; r < 4; ++r)
            hrow[(size_t)r * HID_DIM + n * 16] = f2bf(acc[n][r]);
}

// ---------------- launch 5: agg1 (wave=node, pair-packed gathers) ----------------
// R3 post-mortem: plane split was per-wave-overhead-bound (4x waves, 1/4 work).
// Revert to interleaved [N][128], wave = node. New: half-waves each own one edge
// of a pair -> uint2/lane, 2 edges per gather instr, 16 edges in flight per iter,
// half the shfl+addr work per edge. Junk slots (idx >= n) masked by nmj=0.
__global__ __launch_bounds__(256) void k_agg1(const ushort_t* __restrict__ hb,
                                              const int* __restrict__ ndeg,
                                              const float* __restrict__ dinv,
                                              const ushort_t* __restrict__ es,
                                              const float* __restrict__ b,
                                              ushort_t* __restrict__ hrelu) {
    const int i = blockIdx.x * 4 + (threadIdx.x >> 6);   // 12500*4 = 50000 exact
    const int lane = threadIdx.x & 63;
    const int half = lane >> 5;        // which edge of the pair
    const int c = lane & 31;           // channel group: ch 4c..4c+3
    const float dv = dinv[i];
    const int n = ndeg[i];
    int   sj = 0;
    float nmj = 0.f;
    if (lane < n) {
        sj = (int)__builtin_nontemporal_load(&es[i * CAP + lane]);
        nmj = dinv[sj] * dv;
    }
    float a0 = 0.f, a1 = 0.f, a2 = 0.f, a3 = 0.f;
    int j = 0;
    for (; j + 16 <= n; j += 16) {     // 8 gather instrs, 2 edges each
        int   s0 = __shfl(sj, j + half),      s1 = __shfl(sj, j + 2 + half);
        int   s2 = __shfl(sj, j + 4 + half),  s3 = __shfl(sj, j + 6 + half);
        int   s4 = __shfl(sj, j + 8 + half),  s5 = __shfl(sj, j + 10 + half);
        int   s6 = __shfl(sj, j + 12 + half), s7 = __shfl(sj, j + 14 + half);
        float m0 = __shfl(nmj, j + half),      m1 = __shfl(nmj, j + 2 + half);
        float m2 = __shfl(nmj, j + 4 + half),  m3 = __shfl(nmj, j + 6 + half);
        float m4 = __shfl(nmj, j + 8 + half),  m5 = __shfl(nmj, j + 10 + half);
        float m6 = __shfl(nmj, j + 12 + half), m7 = __shfl(nmj, j + 14 + half);
        uint2 v0 = *(const uint2*)(hb + (size_t)s0 * HID_DIM + 4 * c);
        uint2 v1 = *(const uint2*)(hb + (size_t)s1 * HID_DIM + 4 * c);
        uint2 v2 = *(const uint2*)(hb + (size_t)s2 * HID_DIM + 4 * c);
        uint2 v3 = *(const uint2*)(hb + (size_t)s3 * HID_DIM + 4 * c);
        uint2 v4 = *(const uint2*)(hb + (size_t)s4 * HID_DIM + 4 * c);
        uint2 v5 = *(const uint2*)(hb + (size_t)s5 * HID_DIM + 4 * c);
        uint2 v6 = *(const uint2*)(hb + (size_t)s6 * HID_DIM + 4 * c);
        uint2 v7 = *(const uint2*)(hb + (size_t)s7 * HID_DIM + 4 * c);
        a0 += bf_lo(v0.x) * m0 + bf_lo(v1.x) * m1 + bf_lo(v2.x) * m2 + bf_lo(v3.x) * m3
            + bf_lo(v4.x) * m4 + bf_lo(v5.x) * m5 + bf_lo(v6.x) * m6 + bf_lo(v7.x) * m7;
        a1 += bf_hi(v0.x) * m0 + bf_hi(v1.x) * m1 + bf_hi(v2.x) * m2 + bf_hi(v3.x) * m3
            + bf_hi(v4.x) * m4 + bf_hi(v5.x) * m5 + bf_hi(v6.x) * m6 + bf_hi(v7.x) * m7;
        a2 += bf_lo(v0.y) * m0 + bf_lo(v1.y) * m1 + bf_lo(v2.y) * m2 + bf_lo(v3.y) * m3
            + bf_lo(v4.y) * m4 + bf_lo(v5.y) * m5 + bf_lo(v6.y) * m6 + bf_lo(v7.y) * m7;
        a3 += bf_hi(v0.y) * m0 + bf_hi(v1.y) * m1 + bf_hi(v2.y) * m2 + bf_hi(v3.y) * m3
            + bf_hi(v4.y) * m4 + bf_hi(v5.y) * m5 + bf_hi(v6.y) * m6 + bf_hi(v7.y) * m7;
    }
    for (; j < n; j += 2) {            // tail: 2 edges per instr, junk masked
        int   s = __shfl(sj, j + half);
        float m = __shfl(nmj, j + half);
        uint2 v = *(const uint2*)(hb + (size_t)s * HID_DIM + 4 * c);
        a0 += bf_lo(v.x) * m; a1 += bf_hi(v.x) * m;
        a2 += bf_lo(v.y) * m; a3 += bf_hi(v.y) * m;
    }
    a0 += __shfl_xor(a0, 32); a1 += __shfl_xor(a1, 32);
    a2 += __shfl_xor(a2, 32); a3 += __shfl_xor(a3, 32);
    if (lane < 32) {
        uint2 u = *(const uint2*)(hb + (size_t)i * HID_DIM + 4 * c);   // self loop
        const float dvv = dv * dv;
        float r0 = a0 + bf_lo(u.x) * dvv + b[4 * c];
        float r1 = a1 + bf_hi(u.x) * dvv + b[4 * c + 1];
        float r2 = a2 + bf_lo(u.y) * dvv + b[4 * c + 2];
        float r3 = a3 + bf_hi(u.y) * dvv + b[4 * c + 3];
        r0 = fmaxf(r0, 0.f); r1 = fmaxf(r1, 0.f);
        r2 = fmaxf(r2, 0.f); r3 = fmaxf(r3, 0.f);
        uint2 o;
        o.x = ((uint_t)f2bf(r1) << 16) | f2bf(r0);
        o.y = ((uint_t)f2bf(r3) << 16) | f2bf(r2);
        *(uint2*)(hrelu + (size_t)i * HID_DIM + 4 * c) = o;
    }
}

// ---------------- launch 6: gemm2 (MFMA): h2(bf16, [N][64]) = hrelu @ W2 ----------------
__global__ __launch_bounds__(64) void k_gemm2(const ushort_t* __restrict__ hrelu,
                                              const ushort_t* __restrict__ w2t,
                                              ushort_t* __restrict__ h2) {
    const int lane = threadIdx.x;
    const int l15 = lane & 15, quad = lane >> 4;
    const int row = blockIdx.x * 16 + l15;
    f32x4 acc[4];
#pragma unroll
    for (int n = 0; n < 4; ++n) acc[n] = (f32x4){0.f, 0.f, 0.f, 0.f};
    const ushort_t* arow = hrelu + (size_t)row * HID_DIM + quad * 8;
    const ushort_t* wbase = w2t + quad * 8;
#pragma unroll
    for (int t = 0; t < 4; ++t) {
        bf16x8 a = *(const bf16x8*)(arow + t * 32);
#pragma unroll
        for (int n = 0; n < 4; ++n) {
            bf16x8 b = *(const bf16x8*)(wbase + (n * 16 + l15) * HID_DIM + t * 32);
            acc[n] = __builtin_amdgcn_mfma_f32_16x16x32_bf16(a, b, acc[n], 0, 0, 0);
        }
    }
    ushort_t* orow = h2 + ((size_t)blockIdx.x * 16 + quad * 4) * OUT_DIM + l15;
#pragma unroll
    for (int n = 0; n < 4; ++n)
#pragma unroll
        for (int r = 0; r < 4; ++r)
            orow[(size_t)r * OUT_DIM + n * 16] = f2bf(acc[n][r]);
}

// ---------------- launch 7: agg2 (wave=node, pair-packed gathers) ----------------
__global__ __launch_bounds__(256) void k_agg2(const ushort_t* __restrict__ h2,
                                              const int* __restrict__ ndeg,
                                              const float* __restrict__ dinv,
                                              const ushort_t* __restrict__ es,
                                              const float* __restrict__ b,
                                              float* __restrict__ out) {
    const int i = blockIdx.x * 4 + (threadIdx.x >> 6);
    const int lane = threadIdx.x & 63;
    const int half = lane >> 5;        // which edge of the pair
    const int c = lane & 31;           // channel pair: ch 2c, 2c+1
    const float dv = dinv[i];
    const int n = ndeg[i];
    int   sj = 0;
    float nmj = 0.f;
    if (lane < n) {
        sj = (int)__builtin_nontemporal_load(&es[i * CAP + lane]);
        nmj = dinv[sj] * dv;
    }
    float a0 = 0.f, a1 = 0.f;
    int j = 0;
    for (; j + 16 <= n; j += 16) {     // 8 gather instrs, 2 edges each
        int   s0 = __shfl(sj, j + half),      s1 = __shfl(sj, j + 2 + half);
        int   s2 = __shfl(sj, j + 4 + half),  s3 = __shfl(sj, j + 6 + half);
        int   s4 = __shfl(sj, j + 8 + half),  s5 = __shfl(sj, j + 10 + half);
        int   s6 = __shfl(sj, j + 12 + half), s7 = __shfl(sj, j + 14 + half);
        float m0 = __shfl(nmj, j + half),      m1 = __shfl(nmj, j + 2 + half);
        float m2 = __shfl(nmj, j + 4 + half),  m3 = __shfl(nmj, j + 6 + half);
        float m4 = __shfl(nmj, j + 8 + half),  m5 = __shfl(nmj, j + 10 + half);
        float m6 = __shfl(nmj, j + 12 + half), m7 = __shfl(nmj, j + 14 + half);
        uint_t v0 = *(const uint_t*)(h2 + (size_t)s0 * OUT_DIM + 2 * c);
        uint_t v1 = *(const uint_t*)(h2 + (size_t)s1 * OUT_DIM + 2 * c);
        uint_t v2 = *(const uint_t*)(h2 + (size_t)s2 * OUT_DIM + 2 * c);
        uint_t v3 = *(const uint_t*)(h2 + (size_t)s3 * OUT_DIM + 2 * c);
        uint_t v4 = *(const uint_t*)(h2 + (size_t)s4 * OUT_DIM + 2 * c);
        uint_t v5 = *(const uint_t*)(h2 + (size_t)s5 * OUT_DIM + 2 * c);
        uint_t v6 = *(const uint_t*)(h2 + (size_t)s6 * OUT_DIM + 2 * c);
        uint_t v7 = *(const uint_t*)(h2 + (size_t)s7 * OUT_DIM + 2 * c);
        a0 += bf_lo(v0) * m0 + bf_lo(v1) * m1 + bf_lo(v2) * m2 + bf_lo(v3) * m3
            + bf_lo(v4) * m4 + bf_lo(v5) * m5 + bf_lo(v6) * m6 + bf_lo(v7) * m7;
        a1 += bf_hi(v0) * m0 + bf_hi(v1) * m1 + bf_hi(v2) * m2 + bf_hi(v3) * m3
            + bf_hi(v4) * m4 + bf_hi(v5) * m5 + bf_hi(v6) * m6 + bf_hi(v7) * m7;
    }
    for (; j < n; j += 2) {
        int   s = __shfl(sj, j + half);
        float m = __shfl(nmj, j + half);
        uint_t v = *(const uint_t*)(h2 + (size_t)s * OUT_DIM + 2 * c);
        a0 += bf_lo(v) * m;
        a1 += bf_hi(v) * m;
    }
    a0 += __shfl_xor(a0, 32);
    a1 += __shfl_xor(a1, 32);
    if (lane < 32) {
        uint_t u = *(const uint_t*)(h2 + (size_t)i * OUT_DIM + 2 * c);   // self loop
        float2 r;
        r.x = a0 + bf_lo(u) * dv * dv + b[2 * c];
        r.y = a1 + bf_hi(u) * dv * dv + b[2 * c + 1];
        *(float2*)(out + (size_t)i * OUT_DIM + 2 * c) = r;
    }
}

extern "C" void kernel_launch(void* const* d_in, const int* in_sizes, int n_in,
                              void* d_out, int out_size, void* d_ws, size_t ws_size,
                              hipStream_t stream) {
    const float* x   = (const float*)d_in[0];
    const int*   ei  = (const int*)d_in[1];    // [2, E] int32
    const float* W1  = (const float*)d_in[2];
    const float* b1  = (const float*)d_in[3];
    const float* W2  = (const float*)d_in[4];
    const float* b2  = (const float*)d_in[5];
    float* out = (float*)d_out;

    const int* srcs = ei;             // edge_index[0]
    const int* dsts = ei + N_EDGES;   // edge_index[1]

    // workspace (~43 MB)
    char* ws = (char*)d_ws;
    size_t o = 0;
    auto alloc = [&](size_t bytes) { void* p = ws + o; o = (o + bytes + 511) & ~size_t(511); return p; };
    int*      bin_cur = (int*)   alloc(K_BINS * 4);
    float*    dinv  = (float*)   alloc(N_NODES * 4);
    int*      ndeg  = (int*)     alloc(N_NODES * 4);
    ushort_t* es    = (ushort_t*)alloc((size_t)K_BINS * NPB * CAP * 2);  // padded to 50176 nodes
    uint_t*   binbuf= (uint_t*)  alloc((size_t)K_BINS * BINCAP * 4);     // 4 MB
    ushort_t* w1t   = (ushort_t*)alloc((size_t)IN_DIM * HID_DIM * 2);
    ushort_t* w2t   = (ushort_t*)alloc((size_t)HID_DIM * OUT_DIM * 2);
    ushort_t* hb    = (ushort_t*)alloc((size_t)N_NODES * HID_DIM * 2);
    ushort_t* hrelu = (ushort_t*)alloc((size_t)N_NODES * HID_DIM * 2);
    ushort_t* h2    = (ushort_t*)alloc((size_t)N_NODES * OUT_DIM * 2);

    hipMemsetAsync(bin_cur, 0, K_BINS * 4, stream);
    k_init  <<<160, 256, 0, stream>>>(W1, w1t, W2, w2t);
    k_bin   <<<N_BINWG, 256, 0, stream>>>(srcs, dsts, bin_cur, binbuf);
    k_fill  <<<K_BINS, 256, 0, stream>>>(bin_cur, binbuf, es, dinv, ndeg);
    k_gemm1 <<<N_NODES / 16, 64, 0, stream>>>(x, w1t, hb);
    k_agg1  <<<N_NODES / 4, 256, 0, stream>>>(hb, ndeg, dinv, es, b1, hrelu);
    k_gemm2 <<<N_NODES / 16, 64, 0, stream>>>(hrelu, w2t, h2);
    k_agg2  <<<N_NODES / 4, 256, 0, stream>>>(h2, ndeg, dinv, es, b2, out);
}

// Round 5
// 219.883 us; speedup vs baseline: 1.1919x; 1.0046x over previous
//
#include <hip/hip_runtime.h>

#define N_NODES 50000
#define N_EDGES 800000
#define IN_DIM 256
#define HID_DIM 128
#define OUT_DIM 64
#define CAP 64      // per-node bucket capacity; deg ~Poisson(16), max over 50k ~40

// two-phase binning
#define K_BINS 256
#define NPB 196     // nodes per bin: 256*196 = 50176 >= 50000
#define BINCAP 4096 // expected 3125/bin, sigma ~56 -> 17-sigma headroom
#define CHUNK 2048  // edges per bin workgroup (R5: was 4096; 391 wgs -> 2x occupancy)
#define N_BINWG 391 // ceil(800000/2048)
#define N_WBLK 160  // weight-init blocks in fused launch A
#define N_G1BLK 782 // ceil(50000/64) 4-wave gemm1 blocks in fused launch B

typedef __bf16 bf16x8 __attribute__((ext_vector_type(8)));
typedef float f32x4 __attribute__((ext_vector_type(4)));
typedef unsigned short u16x8 __attribute__((ext_vector_type(8)));
typedef unsigned short ushort_t;
typedef unsigned int uint_t;

// float -> bf16 bits, round-to-nearest-even (finite values)
__device__ __forceinline__ ushort_t f2bf(float f) {
    uint_t u = __float_as_uint(f);
    return (ushort_t)((u + 0x7fffu + ((u >> 16) & 1u)) >> 16);
}
__device__ __forceinline__ float bf_lo(uint_t u) { return __uint_as_float(u << 16); }
__device__ __forceinline__ float bf_hi(uint_t u) { return __uint_as_float(u & 0xffff0000u); }

// ---------------- launch 2 (fused A): weight cast/transpose + edge binning ----------------
// blocks [0,160): weights; blocks [160, 160+391): bin edges. Mutually independent,
// bin is latency-bound (LDS atomics + scattered stores) and overlaps init's copies.
__global__ __launch_bounds__(256) void k_binit(const float* __restrict__ W1,
                                               ushort_t* __restrict__ w1t,
                                               const float* __restrict__ W2,
                                               ushort_t* __restrict__ w2t,
                                               const int* __restrict__ srcs,
                                               const int* __restrict__ dsts,
                                               int* __restrict__ bin_cur,
                                               uint_t* __restrict__ binbuf) {
    const int bid = blockIdx.x;
    const int t = threadIdx.x;
    if (bid < N_WBLK) {
        if (bid < 128) {                   // W1 [256x128] -> w1t [128x256] bf16
            int id = bid * 256 + t;
            int k = id >> 7, c = id & 127;
            w1t[c * IN_DIM + k] = f2bf(W1[id]);
        } else {                           // W2 [128x64] -> w2t [64x128] bf16
            int id = (bid - 128) * 256 + t;
            int k = id >> 6, c = id & 63;
            w2t[c * HID_DIM + k] = f2bf(W2[id]);
        }
        return;
    }
    // ---- bin part: wg = bid - N_WBLK, CHUNK=2048, 8 records/thread ----
    __shared__ int lcnt[K_BINS];
    __shared__ int lbase[K_BINS];
    lcnt[t] = 0;
    __syncthreads();
    const int start = (bid - N_WBLK) * CHUNK;
    int b_[8]; int p_[8]; uint_t rec_[8];
#pragma unroll
    for (int k = 0; k < 8; ++k) {
        int e = start + t + k * 256;
        bool ok = (e < N_EDGES);
        int d = ok ? dsts[e] : 0;
        int s = ok ? srcs[e] : 0;
        int b = d / NPB;                   // magic-mul, NPB is compile-time
        b_[k] = ok ? b : -1;
        p_[k] = ok ? atomicAdd(&lcnt[b], 1) : 0;
        rec_[k] = (uint_t)s | ((uint_t)(d - b * NPB) << 16);  // src < 65536, dl < 196
    }
    __syncthreads();
    lbase[t] = atomicAdd(&bin_cur[t], lcnt[t]);   // 256 atomics/wg
    __syncthreads();
#pragma unroll
    for (int k = 0; k < 8; ++k) {
        if (b_[k] >= 0) {
            int pos = lbase[b_[k]] + p_[k];
            if (pos < BINCAP) binbuf[(size_t)b_[k] * BINCAP + pos] = rec_[k];
        }
    }
}

// ---------------- launch 3 (fused B): fill es buckets + gemm1 ----------------
// blocks [0,256): fill (one wg per bin, LDS scatter -> dense 25 KB dump);
// blocks [256, 256+782): gemm1, 4 waves x 16-row MFMA tiles. Independent halves:
// fill is latency-bound, gemm1 keeps the CUs busy under it.
__global__ __launch_bounds__(256) void k_fillg1(const int* __restrict__ bin_cur,
                                                const uint_t* __restrict__ binbuf,
                                                ushort_t* __restrict__ es,
                                                float* __restrict__ dinv,
                                                int* __restrict__ ndeg,
                                                const float* __restrict__ x,
                                                const ushort_t* __restrict__ w1t,
                                                ushort_t* __restrict__ hb) {
    const int bid = blockIdx.x;
    const int t = threadIdx.x;
    if (bid < K_BINS) {
        // ---- fill part ----
        __shared__ int cnt[NPB];
        __shared__ __align__(16) ushort_t pay[NPB][CAP];   // 25088 B
        const int b = bid;
        if (t < NPB) cnt[t] = 0;
        __syncthreads();
        const int n = min(bin_cur[b], BINCAP);
        const uint_t* rec = binbuf + (size_t)b * BINCAP;
        for (int e = t; e < n; e += 256) {
            uint_t r = rec[e];
            int dl = r >> 16;
            int p = atomicAdd(&cnt[dl], 1);
            if (p < CAP) pay[dl][p] = (ushort_t)(r & 0xffffu);
        }
        __syncthreads();
        uint4* gdst = (uint4*)(es + (size_t)b * NPB * CAP);
        const uint4* lsrc = (const uint4*)&pay[0][0];
        for (int i = t; i < NPB * CAP / 8; i += 256) gdst[i] = lsrc[i];
        if (t < NPB) {
            int node = b * NPB + t;
            if (node < N_NODES) {
                int deg = cnt[t];
                dinv[node] = rsqrtf((float)(deg + 1));
                ndeg[node] = min(deg, CAP);
            }
        }
        return;
    }
    // ---- gemm1 part: wave = one 16-row tile; hb(bf16,[N][128]) = x @ W1 ----
    const int wave = t >> 6;
    const int lane = t & 63;
    const int l15 = lane & 15, quad = lane >> 4;
    const int tbase = (bid - K_BINS) * 64 + wave * 16;
    const int row = min(tbase + l15, N_NODES - 1);   // clamp tail reads
    f32x4 acc[8];
#pragma unroll
    for (int n = 0; n < 8; ++n) acc[n] = (f32x4){0.f, 0.f, 0.f, 0.f};
    const float* xrow = x + (size_t)row * IN_DIM + quad * 8;
    const ushort_t* wbase = w1t + quad * 8;
#pragma unroll
    for (int tk = 0; tk < 8; ++tk) {
        const float4* xp = (const float4*)(xrow + tk * 32);
        float4 f0 = xp[0], f1 = xp[1];
        u16x8 au;
        au[0] = f2bf(f0.x); au[1] = f2bf(f0.y); au[2] = f2bf(f0.z); au[3] = f2bf(f0.w);
        au[4] = f2bf(f1.x); au[5] = f2bf(f1.y); au[6] = f2bf(f1.z); au[7] = f2bf(f1.w);
        bf16x8 a = __builtin_bit_cast(bf16x8, au);
#pragma unroll
        for (int n = 0; n < 8; ++n) {
            bf16x8 b = *(const bf16x8*)(wbase + (n * 16 + l15) * IN_DIM + tk * 32);
            acc[n] = __builtin_amdgcn_mfma_f32_16x16x32_bf16(a, b, acc[n], 0, 0, 0);
        }
    }
    // C/D layout: col = lane&15, row = quad*4 + r  [measured m89/m91]
    const int row0 = tbase + quad * 4;
    ushort_t* hrow = hb + (size_t)row0 * HID_DIM + l15;
#pragma unroll
    for (int n = 0; n < 8; ++n)
#pragma unroll
        for (int r = 0; r < 4; ++r)
            if (row0 + r < N_NODES)
                hrow[(size_t)r * HID_DIM + n * 16] = f2bf(acc[n][r]);
}

// ---------------- launch 4: agg1 (wave=node, pair-packed gathers) ----------------
// Half-waves each own one edge of a pair -> uint2/lane, 2 edges per gather instr,
// 16 edges in flight per iter. Junk slots (idx >= n) masked by nmj=0.
__global__ __launch_bounds__(256) void k_agg1(const ushort_t* __restrict__ hb,
                                              const int* __restrict__ ndeg,
                                              const float* __restrict__ dinv,
                                              const ushort_t* __restrict__ es,
                                              const float* __restrict__ b,
                                              ushort_t* __restrict__ hrelu) {
    const int i = blockIdx.x * 4 + (threadIdx.x >> 6);   // 12500*4 = 50000 exact
    const int lane = threadIdx.x & 63;
    const int half = lane >> 5;        // which edge of the pair
    const int c = lane & 31;           // channel group: ch 4c..4c+3
    const float dv = dinv[i];
    const int n = ndeg[i];
    int   sj = 0;
    float nmj = 0.f;
    if (lane < n) {
        sj = (int)__builtin_nontemporal_load(&es[i * CAP + lane]);
        nmj = dinv[sj] * dv;
    }
    float a0 = 0.f, a1 = 0.f, a2 = 0.f, a3 = 0.f;
    int j = 0;
    for (; j + 16 <= n; j += 16) {     // 8 gather instrs, 2 edges each
        int   s0 = __shfl(sj, j + half),      s1 = __shfl(sj, j + 2 + half);
        int   s2 = __shfl(sj, j + 4 + half),  s3 = __shfl(sj, j + 6 + half);
        int   s4 = __shfl(sj, j + 8 + half),  s5 = __shfl(sj, j + 10 + half);
        int   s6 = __shfl(sj, j + 12 + half), s7 = __shfl(sj, j + 14 + half);
        float m0 = __shfl(nmj, j + half),      m1 = __shfl(nmj, j + 2 + half);
        float m2 = __shfl(nmj, j + 4 + half),  m3 = __shfl(nmj, j + 6 + half);
        float m4 = __shfl(nmj, j + 8 + half),  m5 = __shfl(nmj, j + 10 + half);
        float m6 = __shfl(nmj, j + 12 + half), m7 = __shfl(nmj, j + 14 + half);
        uint2 v0 = *(const uint2*)(hb + (size_t)s0 * HID_DIM + 4 * c);
        uint2 v1 = *(const uint2*)(hb + (size_t)s1 * HID_DIM + 4 * c);
        uint2 v2 = *(const uint2*)(hb + (size_t)s2 * HID_DIM + 4 * c);
        uint2 v3 = *(const uint2*)(hb + (size_t)s3 * HID_DIM + 4 * c);
        uint2 v4 = *(const uint2*)(hb + (size_t)s4 * HID_DIM + 4 * c);
        uint2 v5 = *(const uint2*)(hb + (size_t)s5 * HID_DIM + 4 * c);
        uint2 v6 = *(const uint2*)(hb + (size_t)s6 * HID_DIM + 4 * c);
        uint2 v7 = *(const uint2*)(hb + (size_t)s7 * HID_DIM + 4 * c);
        a0 += bf_lo(v0.x) * m0 + bf_lo(v1.x) * m1 + bf_lo(v2.x) * m2 + bf_lo(v3.x) * m3
            + bf_lo(v4.x) * m4 + bf_lo(v5.x) * m5 + bf_lo(v6.x) * m6 + bf_lo(v7.x) * m7;
        a1 += bf_hi(v0.x) * m0 + bf_hi(v1.x) * m1 + bf_hi(v2.x) * m2 + bf_hi(v3.x) * m3
            + bf_hi(v4.x) * m4 + bf_hi(v5.x) * m5 + bf_hi(v6.x) * m6 + bf_hi(v7.x) * m7;
        a2 += bf_lo(v0.y) * m0 + bf_lo(v1.y) * m1 + bf_lo(v2.y) * m2 + bf_lo(v3.y) * m3
            + bf_lo(v4.y) * m4 + bf_lo(v5.y) * m5 + bf_lo(v6.y) * m6 + bf_lo(v7.y) * m7;
        a3 += bf_hi(v0.y) * m0 + bf_hi(v1.y) * m1 + bf_hi(v2.y) * m2 + bf_hi(v3.y) * m3
            + bf_hi(v4.y) * m4 + bf_hi(v5.y) * m5 + bf_hi(v6.y) * m6 + bf_hi(v7.y) * m7;
    }
    for (; j < n; j += 2) {            // tail: 2 edges per instr, junk masked
        int   s = __shfl(sj, j + half);
        float m = __shfl(nmj, j + half);
        uint2 v = *(const uint2*)(hb + (size_t)s * HID_DIM + 4 * c);
        a0 += bf_lo(v.x) * m; a1 += bf_hi(v.x) * m;
        a2 += bf_lo(v.y) * m; a3 += bf_hi(v.y) * m;
    }
    a0 += __shfl_xor(a0, 32); a1 += __shfl_xor(a1, 32);
    a2 += __shfl_xor(a2, 32); a3 += __shfl_xor(a3, 32);
    if (lane < 32) {
        uint2 u = *(const uint2*)(hb + (size_t)i * HID_DIM + 4 * c);   // self loop
        const float dvv = dv * dv;
        float r0 = a0 + bf_lo(u.x) * dvv + b[4 * c];
        float r1 = a1 + bf_hi(u.x) * dvv + b[4 * c + 1];
        float r2 = a2 + bf_lo(u.y) * dvv + b[4 * c + 2];
        float r3 = a3 + bf_hi(u.y) * dvv + b[4 * c + 3];
        r0 = fmaxf(r0, 0.f); r1 = fmaxf(r1, 0.f);
        r2 = fmaxf(r2, 0.f); r3 = fmaxf(r3, 0.f);
        uint2 o;
        o.x = ((uint_t)f2bf(r1) << 16) | f2bf(r0);
        o.y = ((uint_t)f2bf(r3) << 16) | f2bf(r2);
        *(uint2*)(hrelu + (size_t)i * HID_DIM + 4 * c) = o;
    }
}

// ---------------- launch 5: gemm2 (MFMA, 4-wave blocks): h2(bf16,[N][64]) = hrelu @ W2 ----------------
__global__ __launch_bounds__(256) void k_gemm2(const ushort_t* __restrict__ hrelu,
                                               const ushort_t* __restrict__ w2t,
                                               ushort_t* __restrict__ h2) {
    const int t = threadIdx.x;
    const int wave = t >> 6;
    const int lane = t & 63;
    const int l15 = lane & 15, quad = lane >> 4;
    const int tbase = blockIdx.x * 64 + wave * 16;
    const int row = min(tbase + l15, N_NODES - 1);
    f32x4 acc[4];
#pragma unroll
    for (int n = 0; n < 4; ++n) acc[n] = (f32x4){0.f, 0.f, 0.f, 0.f};
    const ushort_t* arow = hrelu + (size_t)row * HID_DIM + quad * 8;
    const ushort_t* wbase = w2t + quad * 8;
#pragma unroll
    for (int tk = 0; tk < 4; ++tk) {
        bf16x8 a = *(const bf16x8*)(arow + tk * 32);
#pragma unroll
        for (int n = 0; n < 4; ++n) {
            bf16x8 b = *(const bf16x8*)(wbase + (n * 16 + l15) * HID_DIM + tk * 32);
            acc[n] = __builtin_amdgcn_mfma_f32_16x16x32_bf16(a, b, acc[n], 0, 0, 0);
        }
    }
    const int row0 = tbase + quad * 4;
    ushort_t* orow = h2 + (size_t)row0 * OUT_DIM + l15;
#pragma unroll
    for (int n = 0; n < 4; ++n)
#pragma unroll
        for (int r = 0; r < 4; ++r)
            if (row0 + r < N_NODES)
                orow[(size_t)r * OUT_DIM + n * 16] = f2bf(acc[n][r]);
}

// ---------------- launch 6: agg2 (wave=node, pair-packed gathers) ----------------
__global__ __launch_bounds__(256) void k_agg2(const ushort_t* __restrict__ h2,
                                              const int* __restrict__ ndeg,
                                              const float* __restrict__ dinv,
                                              const ushort_t* __restrict__ es,
                                              const float* __restrict__ b,
                                              float* __restrict__ out) {
    const int i = blockIdx.x * 4 + (threadIdx.x >> 6);
    const int lane = threadIdx.x & 63;
    const int half = lane >> 5;        // which edge of the pair
    const int c = lane & 31;           // channel pair: ch 2c, 2c+1
    const float dv = dinv[i];
    const int n = ndeg[i];
    int   sj = 0;
    float nmj = 0.f;
    if (lane < n) {
        sj = (int)__builtin_nontemporal_load(&es[i * CAP + lane]);
        nmj = dinv[sj] * dv;
    }
    float a0 = 0.f, a1 = 0.f;
    int j = 0;
    for (; j + 16 <= n; j += 16) {     // 8 gather instrs, 2 edges each
        int   s0 = __shfl(sj, j + half),      s1 = __shfl(sj, j + 2 + half);
        int   s2 = __shfl(sj, j + 4 + half),  s3 = __shfl(sj, j + 6 + half);
        int   s4 = __shfl(sj, j + 8 + half),  s5 = __shfl(sj, j + 10 + half);
        int   s6 = __shfl(sj, j + 12 + half), s7 = __shfl(sj, j + 14 + half);
        float m0 = __shfl(nmj, j + half),      m1 = __shfl(nmj, j + 2 + half);
        float m2 = __shfl(nmj, j + 4 + half),  m3 = __shfl(nmj, j + 6 + half);
        float m4 = __shfl(nmj, j + 8 + half),  m5 = __shfl(nmj, j + 10 + half);
        float m6 = __shfl(nmj, j + 12 + half), m7 = __shfl(nmj, j + 14 + half);
        uint_t v0 = *(const uint_t*)(h2 + (size_t)s0 * OUT_DIM + 2 * c);
        uint_t v1 = *(const uint_t*)(h2 + (size_t)s1 * OUT_DIM + 2 * c);
        uint_t v2 = *(const uint_t*)(h2 + (size_t)s2 * OUT_DIM + 2 * c);
        uint_t v3 = *(const uint_t*)(h2 + (size_t)s3 * OUT_DIM + 2 * c);
        uint_t v4 = *(const uint_t*)(h2 + (size_t)s4 * OUT_DIM + 2 * c);
        uint_t v5 = *(const uint_t*)(h2 + (size_t)s5 * OUT_DIM + 2 * c);
        uint_t v6 = *(const uint_t*)(h2 + (size_t)s6 * OUT_DIM + 2 * c);
        uint_t v7 = *(const uint_t*)(h2 + (size_t)s7 * OUT_DIM + 2 * c);
        a0 += bf_lo(v0) * m0 + bf_lo(v1) * m1 + bf_lo(v2) * m2 + bf_lo(v3) * m3
            + bf_lo(v4) * m4 + bf_lo(v5) * m5 + bf_lo(v6) * m6 + bf_lo(v7) * m7;
        a1 += bf_hi(v0) * m0 + bf_hi(v1) * m1 + bf_hi(v2) * m2 + bf_hi(v3) * m3
            + bf_hi(v4) * m4 + bf_hi(v5) * m5 + bf_hi(v6) * m6 + bf_hi(v7) * m7;
    }
    for (; j < n; j += 2) {
        int   s = __shfl(sj, j + half);
        float m = __shfl(nmj, j + half);
        uint_t v = *(const uint_t*)(h2 + (size_t)s * OUT_DIM + 2 * c);
        a0 += bf_lo(v) * m;
        a1 += bf_hi(v) * m;
    }
    a0 += __shfl_xor(a0, 32);
    a1 += __shfl_xor(a1, 32);
    if (lane < 32) {
        uint_t u = *(const uint_t*)(h2 + (size_t)i * OUT_DIM + 2 * c);   // self loop
        float2 r;
        r.x = a0 + bf_lo(u) * dv * dv + b[2 * c];
        r.y = a1 + bf_hi(u) * dv * dv + b[2 * c + 1];
        *(float2*)(out + (size_t)i * OUT_DIM + 2 * c) = r;
    }
}

extern "C" void kernel_launch(void* const* d_in, const int* in_sizes, int n_in,
                              void* d_out, int out_size, void* d_ws, size_t ws_size,
                              hipStream_t stream) {
    const float* x   = (const float*)d_in[0];
    const int*   ei  = (const int*)d_in[1];    // [2, E] int32
    const float* W1  = (const float*)d_in[2];
    const float* b1  = (const float*)d_in[3];
    const float* W2  = (const float*)d_in[4];
    const float* b2  = (const float*)d_in[5];
    float* out = (float*)d_out;

    const int* srcs = ei;             // edge_index[0]
    const int* dsts = ei + N_EDGES;   // edge_index[1]

    // workspace (~43 MB)
    char* ws = (char*)d_ws;
    size_t o = 0;
    auto alloc = [&](size_t bytes) { void* p = ws + o; o = (o + bytes + 511) & ~size_t(511); return p; };
    int*      bin_cur = (int*)   alloc(K_BINS * 4);
    float*    dinv  = (float*)   alloc(N_NODES * 4);
    int*      ndeg  = (int*)     alloc(N_NODES * 4);
    ushort_t* es    = (ushort_t*)alloc((size_t)K_BINS * NPB * CAP * 2);  // padded to 50176 nodes
    uint_t*   binbuf= (uint_t*)  alloc((size_t)K_BINS * BINCAP * 4);     // 4 MB
    ushort_t* w1t   = (ushort_t*)alloc((size_t)IN_DIM * HID_DIM * 2);
    ushort_t* w2t   = (ushort_t*)alloc((size_t)HID_DIM * OUT_DIM * 2);
    ushort_t* hb    = (ushort_t*)alloc((size_t)N_NODES * HID_DIM * 2);
    ushort_t* hrelu = (ushort_t*)alloc((size_t)N_NODES * HID_DIM * 2);
    ushort_t* h2    = (ushort_t*)alloc((size_t)N_NODES * OUT_DIM * 2);

    hipMemsetAsync(bin_cur, 0, K_BINS * 4, stream);
    k_binit <<<N_WBLK + N_BINWG, 256, 0, stream>>>(W1, w1t, W2, w2t, srcs, dsts, bin_cur, binbuf);
    k_fillg1<<<K_BINS + N_G1BLK, 256, 0, stream>>>(bin_cur, binbuf, es, dinv, ndeg, x, w1t, hb);
    k_agg1  <<<N_NODES / 4, 256, 0, stream>>>(hb, ndeg, dinv, es, b1, hrelu);
    k_gemm2 <<<N_G1BLK, 256, 0, stream>>>(hrelu, w2t, h2);
    k_agg2  <<<N_NODES / 4, 256, 0, stream>>>(h2, ndeg, dinv, es, b2, out);
}